// Round 1
// baseline (637.875 us; speedup 1.0000x reference)
//
#include <hip/hip_runtime.h>

#define IMG_H 224
#define IMG_W 224
#define TILE  32          // output pixels per block (32x32), 7x7 tiles per image

// ---- ordered-uint mapping for float atomic min/max ----
__device__ __forceinline__ unsigned int ford(float f) {
    unsigned int u = __float_as_uint(f);
    return (u & 0x80000000u) ? ~u : (u | 0x80000000u);
}
__device__ __forceinline__ float funord(unsigned int u) {
    unsigned int v = (u & 0x80000000u) ? (u & 0x7FFFFFFFu) : ~u;
    return __uint_as_float(v);
}

__global__ void init_red(unsigned int* red) {
    red[0] = 0xFFFFFFFFu;  // rec min
    red[1] = 0u;           // rec max
    red[2] = 0xFFFFFFFFu;  // ves min
    red[3] = 0u;           // ves max
}

// One block = 32x32 output pixels of one image. Thread (tx,ty) owns a 2x2 pixel
// quad (matches the Haar 2x2 block structure).
// WRITE=false: reduce global min/max of rec & vesselness.
// WRITE=true : read min/max scalars, write normalized 3-channel output.
template<bool WRITE>
__global__ __launch_bounds__(256)
void frac_kernel(const float* __restrict__ x, float* __restrict__ out,
                 unsigned int* __restrict__ red)
{
    __shared__ float xs[36][37];   // x tile with halo 2 (zero outside image)
    __shared__ float gxs[34][35];  // ix tile with halo 1 (zero outside image)
    __shared__ float gys[34][35];  // iy tile with halo 1
    __shared__ unsigned int wred[4][4];

    const int r0   = blockIdx.y * TILE;
    const int c0   = blockIdx.x * TILE;
    const int bimg = blockIdx.z;
    const int tx = threadIdx.x, ty = threadIdx.y;
    const int tid = ty * 16 + tx;

    const float* xp = x + (size_t)bimg * 3 * IMG_H * IMG_W;  // channel 0 plane

    // ---- stage x tile (halo 2), zeros outside image ----
    for (int i = tid; i < 36 * 36; i += 256) {
        int r = i / 36, c = i % 36;
        int gr = r0 - 2 + r, gc = c0 - 2 + c;
        float v = 0.f;
        if (gr >= 0 && gr < IMG_H && gc >= 0 && gc < IMG_W)
            v = xp[gr * IMG_W + gc];
        xs[r][c] = v;
    }
    __syncthreads();

    // ---- first Sobel stage: ix, iy on halo-1 tile; ZERO outside image ----
    // (replicates SAME zero-padding then truncation of the intermediate)
    for (int i = tid; i < 34 * 34; i += 256) {
        int r = i / 34, c = i % 34;
        int gr = r0 - 1 + r, gc = c0 - 1 + c;
        float vx = 0.f, vy = 0.f;
        if (gr >= 0 && gr < IMG_H && gc >= 0 && gc < IMG_W) {
            vx = (xs[r][c+2]   - xs[r][c])
               + 2.f * (xs[r+1][c+2] - xs[r+1][c])
               + (xs[r+2][c+2] - xs[r+2][c]);
            vy = (xs[r+2][c]   - xs[r][c])
               + 2.f * (xs[r+2][c+1] - xs[r][c+1])
               + (xs[r+2][c+2] - xs[r][c+2]);
        }
        gxs[r][c] = vx;
        gys[r][c] = vy;
    }
    __syncthreads();

    // ---- per-thread 2x2 quad ----
    const float a  = xs[2*ty+2][2*tx+2];
    const float b  = xs[2*ty+2][2*tx+3];
    const float c_ = xs[2*ty+3][2*tx+2];
    const float d  = xs[2*ty+3][2*tx+3];

    // Haar forward (stride-2 VALID, /2), gains, inverse (einsum) -> rec 2x2
    const float h0 = (a + b + c_ + d) * 0.5f;
    const float h1 = (a - b + c_ - d) * 0.5f;
    const float h2 = (a + b - c_ - d) * 0.5f;
    const float h3 = (a - b - c_ + d) * 0.5f;
    const float s0 = 0.1f * h0, s1 = 2.5f * h1, s2 = 2.5f * h2, s3 = 3.5f * h3;
    const float r00 = (s0 + s1 + s2 + s3) * 0.5f;
    const float r01 = (s0 - s1 + s2 - s3) * 0.5f;
    const float r10 = (s0 + s1 - s2 - s3) * 0.5f;
    const float r11 = (s0 - s1 - s2 + s3) * 0.5f;

    // second Sobel stage -> vesselness = |ixx + iyy| at the 4 quad pixels
    float v[2][2];
    #pragma unroll
    for (int sy = 0; sy < 2; ++sy) {
        #pragma unroll
        for (int sx = 0; sx < 2; ++sx) {
            const int ar = 2*ty + sy, ac = 2*tx + sx;
            float ixx = (gxs[ar][ac+2]   - gxs[ar][ac])
                      + 2.f * (gxs[ar+1][ac+2] - gxs[ar+1][ac])
                      + (gxs[ar+2][ac+2] - gxs[ar+2][ac]);
            float iyy = (gys[ar+2][ac]   - gys[ar][ac])
                      + 2.f * (gys[ar+2][ac+1] - gys[ar][ac+1])
                      + (gys[ar+2][ac+2] - gys[ar][ac+2]);
            v[sy][sx] = fabsf(ixx + iyy);
        }
    }

    if constexpr (!WRITE) {
        float rmn = fminf(fminf(r00, r01), fminf(r10, r11));
        float rmx = fmaxf(fmaxf(r00, r01), fmaxf(r10, r11));
        float vmn = fminf(fminf(v[0][0], v[0][1]), fminf(v[1][0], v[1][1]));
        float vmx = fmaxf(fmaxf(v[0][0], v[0][1]), fmaxf(v[1][0], v[1][1]));
        #pragma unroll
        for (int off = 32; off; off >>= 1) {
            rmn = fminf(rmn, __shfl_down(rmn, off));
            rmx = fmaxf(rmx, __shfl_down(rmx, off));
            vmn = fminf(vmn, __shfl_down(vmn, off));
            vmx = fmaxf(vmx, __shfl_down(vmx, off));
        }
        const int wave = tid >> 6, lane = tid & 63;
        if (lane == 0) {
            wred[wave][0] = ford(rmn);
            wred[wave][1] = ford(rmx);
            wred[wave][2] = ford(vmn);
            wred[wave][3] = ford(vmx);
        }
        __syncthreads();
        if (tid == 0) {
            unsigned a0 = min(min(wred[0][0], wred[1][0]), min(wred[2][0], wred[3][0]));
            unsigned a1 = max(max(wred[0][1], wred[1][1]), max(wred[2][1], wred[3][1]));
            unsigned a2 = min(min(wred[0][2], wred[1][2]), min(wred[2][2], wred[3][2]));
            unsigned a3 = max(max(wred[0][3], wred[1][3]), max(wred[2][3], wred[3][3]));
            atomicMin(&red[0], a0);
            atomicMax(&red[1], a1);
            atomicMin(&red[2], a2);
            atomicMax(&red[3], a3);
        }
    } else {
        const float rmin = funord(red[0]);
        const float rmax = funord(red[1]);
        const float vmin = funord(red[2]);
        const float vmax = funord(red[3]);
        const float rsc = 1.f / (rmax - rmin + 1e-6f);
        const float vsc = 1.f / (vmax - vmin + 1e-6f);
        const float m0 = 0.485f, i0 = 1.f / 0.229f;
        const float m1 = 0.456f, i1 = 1.f / 0.224f;
        const float m2 = 0.406f, i2 = 1.f / 0.225f;

        const size_t base = (size_t)bimg * 3 * IMG_H * IMG_W;
        const int py = r0 + 2 * ty;
        const int px = c0 + 2 * tx;

        float2* o;
        // channel 0: structural
        o = (float2*)(out + base + (size_t)py * IMG_W + px);
        *o = make_float2((a  - m0) * i0, (b - m0) * i0);
        o = (float2*)(out + base + (size_t)(py + 1) * IMG_W + px);
        *o = make_float2((c_ - m0) * i0, (d - m0) * i0);
        // channel 1: frequency (min-max normalized rec)
        o = (float2*)(out + base + (size_t)IMG_H * IMG_W + (size_t)py * IMG_W + px);
        *o = make_float2(((r00 - rmin) * rsc - m1) * i1, ((r01 - rmin) * rsc - m1) * i1);
        o = (float2*)(out + base + (size_t)IMG_H * IMG_W + (size_t)(py + 1) * IMG_W + px);
        *o = make_float2(((r10 - rmin) * rsc - m1) * i1, ((r11 - rmin) * rsc - m1) * i1);
        // channel 2: ridge (min-max normalized vesselness)
        o = (float2*)(out + base + (size_t)2 * IMG_H * IMG_W + (size_t)py * IMG_W + px);
        *o = make_float2(((v[0][0] - vmin) * vsc - m2) * i2, ((v[0][1] - vmin) * vsc - m2) * i2);
        o = (float2*)(out + base + (size_t)2 * IMG_H * IMG_W + (size_t)(py + 1) * IMG_W + px);
        *o = make_float2(((v[1][0] - vmin) * vsc - m2) * i2, ((v[1][1] - vmin) * vsc - m2) * i2);
    }
}

extern "C" void kernel_launch(void* const* d_in, const int* in_sizes, int n_in,
                              void* d_out, int out_size, void* d_ws, size_t ws_size,
                              hipStream_t stream) {
    const float* x = (const float*)d_in[0];
    float* out = (float*)d_out;
    unsigned int* red = (unsigned int*)d_ws;

    init_red<<<1, 1, 0, stream>>>(red);

    dim3 grid(IMG_W / TILE, IMG_H / TILE, 256);  // 7 x 7 x 256
    dim3 block(16, 16);
    frac_kernel<false><<<grid, block, 0, stream>>>(x, nullptr, red);
    frac_kernel<true ><<<grid, block, 0, stream>>>(x, out, red);
}

// Round 2
// 105.891 us; speedup vs baseline: 6.0239x; 6.0239x over previous
//
#include <hip/hip_runtime.h>

#define IMG_H 224
#define IMG_W 224
#define TILE  32          // output pixels per block (32x32), 7x7 tiles per image
#define NTILES (7 * 7 * 256)   // 12544 blocks

// ---- ordered-uint mapping for float min/max on uints ----
__device__ __forceinline__ unsigned int ford(float f) {
    unsigned int u = __float_as_uint(f);
    return (u & 0x80000000u) ? ~u : (u | 0x80000000u);
}
__device__ __forceinline__ float funord(unsigned int u) {
    unsigned int v = (u & 0x80000000u) ? (u & 0x7FFFFFFFu) : ~u;
    return __uint_as_float(v);
}

// ws layout: [0..3] final red (uint), [4..] per-block partials as uint4
// partial.x = rec min (ordered), .y = rec max, .z = ves min, .w = ves max

// One block = 32x32 output pixels of one image. Thread (tx,ty) owns a 2x2 pixel
// quad (matches the Haar 2x2 block structure).
// WRITE=false: write per-block partial min/max to ws (no atomics).
// WRITE=true : read final min/max scalars, write normalized 3-channel output.
template<bool WRITE>
__global__ __launch_bounds__(256)
void frac_kernel(const float* __restrict__ x, float* __restrict__ out,
                 unsigned int* __restrict__ red, uint4* __restrict__ partials)
{
    __shared__ float xs[36][37];   // x tile with halo 2 (zero outside image)
    __shared__ float gxs[34][35];  // ix tile with halo 1 (zero outside image)
    __shared__ float gys[34][35];  // iy tile with halo 1
    __shared__ unsigned int wred[4][4];

    const int r0   = blockIdx.y * TILE;
    const int c0   = blockIdx.x * TILE;
    const int bimg = blockIdx.z;
    const int tx = threadIdx.x, ty = threadIdx.y;
    const int tid = ty * 16 + tx;

    const float* xp = x + (size_t)bimg * 3 * IMG_H * IMG_W;  // channel 0 plane

    // ---- stage x tile (halo 2), zeros outside image ----
    for (int i = tid; i < 36 * 36; i += 256) {
        int r = i / 36, c = i % 36;
        int gr = r0 - 2 + r, gc = c0 - 2 + c;
        float v = 0.f;
        if (gr >= 0 && gr < IMG_H && gc >= 0 && gc < IMG_W)
            v = xp[gr * IMG_W + gc];
        xs[r][c] = v;
    }
    __syncthreads();

    // ---- first Sobel stage: ix, iy on halo-1 tile; ZERO outside image ----
    // (replicates SAME zero-padding then truncation of the intermediate)
    for (int i = tid; i < 34 * 34; i += 256) {
        int r = i / 34, c = i % 34;
        int gr = r0 - 1 + r, gc = c0 - 1 + c;
        float vx = 0.f, vy = 0.f;
        if (gr >= 0 && gr < IMG_H && gc >= 0 && gc < IMG_W) {
            vx = (xs[r][c+2]   - xs[r][c])
               + 2.f * (xs[r+1][c+2] - xs[r+1][c])
               + (xs[r+2][c+2] - xs[r+2][c]);
            vy = (xs[r+2][c]   - xs[r][c])
               + 2.f * (xs[r+2][c+1] - xs[r][c+1])
               + (xs[r+2][c+2] - xs[r][c+2]);
        }
        gxs[r][c] = vx;
        gys[r][c] = vy;
    }
    __syncthreads();

    // ---- per-thread 2x2 quad ----
    const float a  = xs[2*ty+2][2*tx+2];
    const float b  = xs[2*ty+2][2*tx+3];
    const float c_ = xs[2*ty+3][2*tx+2];
    const float d  = xs[2*ty+3][2*tx+3];

    // Haar forward (stride-2 VALID, /2), gains, inverse (einsum) -> rec 2x2
    const float h0 = (a + b + c_ + d) * 0.5f;
    const float h1 = (a - b + c_ - d) * 0.5f;
    const float h2 = (a + b - c_ - d) * 0.5f;
    const float h3 = (a - b - c_ + d) * 0.5f;
    const float s0 = 0.1f * h0, s1 = 2.5f * h1, s2 = 2.5f * h2, s3 = 3.5f * h3;
    const float r00 = (s0 + s1 + s2 + s3) * 0.5f;
    const float r01 = (s0 - s1 + s2 - s3) * 0.5f;
    const float r10 = (s0 + s1 - s2 - s3) * 0.5f;
    const float r11 = (s0 - s1 - s2 + s3) * 0.5f;

    // second Sobel stage -> vesselness = |ixx + iyy| at the 4 quad pixels
    float v[2][2];
    #pragma unroll
    for (int sy = 0; sy < 2; ++sy) {
        #pragma unroll
        for (int sx = 0; sx < 2; ++sx) {
            const int ar = 2*ty + sy, ac = 2*tx + sx;
            float ixx = (gxs[ar][ac+2]   - gxs[ar][ac])
                      + 2.f * (gxs[ar+1][ac+2] - gxs[ar+1][ac])
                      + (gxs[ar+2][ac+2] - gxs[ar+2][ac]);
            float iyy = (gys[ar+2][ac]   - gys[ar][ac])
                      + 2.f * (gys[ar+2][ac+1] - gys[ar][ac+1])
                      + (gys[ar+2][ac+2] - gys[ar][ac+2]);
            v[sy][sx] = fabsf(ixx + iyy);
        }
    }

    if constexpr (!WRITE) {
        float rmn = fminf(fminf(r00, r01), fminf(r10, r11));
        float rmx = fmaxf(fmaxf(r00, r01), fmaxf(r10, r11));
        float vmn = fminf(fminf(v[0][0], v[0][1]), fminf(v[1][0], v[1][1]));
        float vmx = fmaxf(fmaxf(v[0][0], v[0][1]), fmaxf(v[1][0], v[1][1]));
        #pragma unroll
        for (int off = 32; off; off >>= 1) {
            rmn = fminf(rmn, __shfl_down(rmn, off));
            rmx = fmaxf(rmx, __shfl_down(rmx, off));
            vmn = fminf(vmn, __shfl_down(vmn, off));
            vmx = fmaxf(vmx, __shfl_down(vmx, off));
        }
        const int wave = tid >> 6, lane = tid & 63;
        if (lane == 0) {
            wred[wave][0] = ford(rmn);
            wred[wave][1] = ford(rmx);
            wred[wave][2] = ford(vmn);
            wred[wave][3] = ford(vmx);
        }
        __syncthreads();
        if (tid == 0) {
            uint4 p;
            p.x = min(min(wred[0][0], wred[1][0]), min(wred[2][0], wred[3][0]));
            p.y = max(max(wred[0][1], wred[1][1]), max(wred[2][1], wred[3][1]));
            p.z = min(min(wred[0][2], wred[1][2]), min(wred[2][2], wred[3][2]));
            p.w = max(max(wred[0][3], wred[1][3]), max(wred[2][3], wred[3][3]));
            const int bindex = (bimg * 7 + (int)blockIdx.y) * 7 + (int)blockIdx.x;
            partials[bindex] = p;   // contention-free store
        }
    } else {
        const float rmin = funord(red[0]);
        const float rmax = funord(red[1]);
        const float vmin = funord(red[2]);
        const float vmax = funord(red[3]);
        const float rsc = 1.f / (rmax - rmin + 1e-6f);
        const float vsc = 1.f / (vmax - vmin + 1e-6f);
        const float m0 = 0.485f, i0 = 1.f / 0.229f;
        const float m1 = 0.456f, i1 = 1.f / 0.224f;
        const float m2 = 0.406f, i2 = 1.f / 0.225f;

        const size_t base = (size_t)bimg * 3 * IMG_H * IMG_W;
        const int py = r0 + 2 * ty;
        const int px = c0 + 2 * tx;

        float2* o;
        // channel 0: structural
        o = (float2*)(out + base + (size_t)py * IMG_W + px);
        *o = make_float2((a  - m0) * i0, (b - m0) * i0);
        o = (float2*)(out + base + (size_t)(py + 1) * IMG_W + px);
        *o = make_float2((c_ - m0) * i0, (d - m0) * i0);
        // channel 1: frequency (min-max normalized rec)
        o = (float2*)(out + base + (size_t)IMG_H * IMG_W + (size_t)py * IMG_W + px);
        *o = make_float2(((r00 - rmin) * rsc - m1) * i1, ((r01 - rmin) * rsc - m1) * i1);
        o = (float2*)(out + base + (size_t)IMG_H * IMG_W + (size_t)(py + 1) * IMG_W + px);
        *o = make_float2(((r10 - rmin) * rsc - m1) * i1, ((r11 - rmin) * rsc - m1) * i1);
        // channel 2: ridge (min-max normalized vesselness)
        o = (float2*)(out + base + (size_t)2 * IMG_H * IMG_W + (size_t)py * IMG_W + px);
        *o = make_float2(((v[0][0] - vmin) * vsc - m2) * i2, ((v[0][1] - vmin) * vsc - m2) * i2);
        o = (float2*)(out + base + (size_t)2 * IMG_H * IMG_W + (size_t)(py + 1) * IMG_W + px);
        *o = make_float2(((v[1][0] - vmin) * vsc - m2) * i2, ((v[1][1] - vmin) * vsc - m2) * i2);
    }
}

// Single-block reduction of the per-block partials -> red[0..3]. ~200 KB read.
__global__ __launch_bounds__(256)
void reduce_partials(const uint4* __restrict__ partials, unsigned int* __restrict__ red)
{
    __shared__ unsigned int wred[4][4];
    const int tid = threadIdx.x;
    unsigned int mn0 = 0xFFFFFFFFu, mx1 = 0u, mn2 = 0xFFFFFFFFu, mx3 = 0u;
    for (int i = tid; i < NTILES; i += 256) {
        uint4 p = partials[i];
        mn0 = min(mn0, p.x);
        mx1 = max(mx1, p.y);
        mn2 = min(mn2, p.z);
        mx3 = max(mx3, p.w);
    }
    #pragma unroll
    for (int off = 32; off; off >>= 1) {
        mn0 = min(mn0, (unsigned int)__shfl_down((int)mn0, off));
        mx1 = max(mx1, (unsigned int)__shfl_down((int)mx1, off));
        mn2 = min(mn2, (unsigned int)__shfl_down((int)mn2, off));
        mx3 = max(mx3, (unsigned int)__shfl_down((int)mx3, off));
    }
    const int wave = tid >> 6, lane = tid & 63;
    if (lane == 0) {
        wred[wave][0] = mn0;
        wred[wave][1] = mx1;
        wred[wave][2] = mn2;
        wred[wave][3] = mx3;
    }
    __syncthreads();
    if (tid == 0) {
        red[0] = min(min(wred[0][0], wred[1][0]), min(wred[2][0], wred[3][0]));
        red[1] = max(max(wred[0][1], wred[1][1]), max(wred[2][1], wred[3][1]));
        red[2] = min(min(wred[0][2], wred[1][2]), min(wred[2][2], wred[3][2]));
        red[3] = max(max(wred[0][3], wred[1][3]), max(wred[2][3], wred[3][3]));
    }
}

extern "C" void kernel_launch(void* const* d_in, const int* in_sizes, int n_in,
                              void* d_out, int out_size, void* d_ws, size_t ws_size,
                              hipStream_t stream) {
    const float* x = (const float*)d_in[0];
    float* out = (float*)d_out;
    unsigned int* red = (unsigned int*)d_ws;           // 4 uints
    uint4* partials = (uint4*)((char*)d_ws + 16);      // NTILES uint4

    dim3 grid(IMG_W / TILE, IMG_H / TILE, 256);  // 7 x 7 x 256
    dim3 block(16, 16);
    frac_kernel<false><<<grid, block, 0, stream>>>(x, nullptr, red, partials);
    reduce_partials<<<1, 256, 0, stream>>>(partials, red);
    frac_kernel<true ><<<grid, block, 0, stream>>>(x, out, red, partials);
}

// Round 3
// 94.365 us; speedup vs baseline: 6.7597x; 1.1222x over previous
//
#include <hip/hip_runtime.h>

#define IMG_H 224
#define IMG_W 224
#define PLANE (IMG_H * IMG_W)    // 50176
#define NTILES (7 * 7 * 256)     // 12544

typedef float fl4 __attribute__((ext_vector_type(4)));

// ---- ordered-uint mapping for float min/max ----
__device__ __forceinline__ unsigned int ford(float f) {
    unsigned int u = __float_as_uint(f);
    return (u & 0x80000000u) ? ~u : (u | 0x80000000u);
}
__device__ __forceinline__ float funord(unsigned int u) {
    unsigned int v = (u & 0x80000000u) ? (u & 0x7FFFFFFFu) : ~u;
    return __uint_as_float(v);
}

// Exact two-stage Sobel vesselness for border-ring pixels (distance 0 from edge).
// xs is the zero-padded staged tile; (lr,lc) = xs coords of the pixel.
__device__ __forceinline__ float ves_exact(const float xs[36][44], int lr, int lc,
                                           int gr, int gc)
{
    float acc = 0.f;
    #pragma unroll
    for (int dr = -1; dr <= 1; ++dr) {
        #pragma unroll
        for (int dc = -1; dc <= 1; ++dc) {
            const int qr = gr + dr, qc = gc + dc;
            if ((unsigned)qr < IMG_H && (unsigned)qc < IMG_W) {
                const int a = lr + dr, b = lc + dc;
                const float gx = (xs[a-1][b+1] - xs[a-1][b-1])
                               + 2.f * (xs[a][b+1] - xs[a][b-1])
                               + (xs[a+1][b+1] - xs[a+1][b-1]);
                const float gy = (xs[a+1][b-1] - xs[a-1][b-1])
                               + 2.f * (xs[a+1][b] - xs[a-1][b])
                               + (xs[a+1][b+1] - xs[a-1][b+1]);
                const float kxw = (float)dc * ((dr == 0) ? 2.f : 1.f);
                const float kyw = (float)dr * ((dc == 0) ? 2.f : 1.f);
                acc += kxw * gx + kyw * gy;
            }
        }
    }
    return fabsf(acc);
}

// Block = 32x32 tile; block(8,16)=128 threads; thread owns 2 rows x 4 cols
// (= two Haar quads side by side). Interior vesselness via composed separable
// 5x5; border ring via exact two-stage.
template<bool WRITE>
__global__ __launch_bounds__(128)
void frac_kernel(const float* __restrict__ x, float* __restrict__ out,
                 const unsigned int* __restrict__ red, uint4* __restrict__ partials)
{
    __shared__ float xs[36][44];   // rows gr0-2.., cols c0-4.. (40 used, pad to 44)
    __shared__ unsigned int wred[2][4];

    const int r0 = blockIdx.y * 32;
    const int c0 = blockIdx.x * 32;
    const int bimg = blockIdx.z;
    const int tx = threadIdx.x;    // 0..7
    const int ty = threadIdx.y;    // 0..15
    const int tid = ty * 8 + tx;

    const float* xp = x + (size_t)bimg * 3 * PLANE;   // channel-0 plane

    // ---- stage 36 rows x 40 cols as float4 (alignment: c0-4 is 16B aligned),
    //      zero outside image; OOB float4s are always fully OOB here.
    for (int i = tid; i < 360; i += 128) {
        const int r = i / 10, c4 = i - 10 * r;
        const int gr = r0 - 2 + r;
        const int gc = c0 - 4 + 4 * c4;
        fl4 v = (fl4)0.f;
        if ((unsigned)gr < IMG_H && (unsigned)gc < IMG_W)
            v = *(const fl4*)(xp + gr * IMG_W + gc);
        *(fl4*)&xs[r][4 * c4] = v;
    }
    __syncthreads();

    // ---- horizontal prefilters over 6 rows x 8 cols per thread:
    // uu = [1,0,-2,0,1], ww = [1,4,6,4,1]
    float uu[6][4], ww[6][4];
    #pragma unroll
    for (int rr = 0; rr < 6; ++rr) {
        float ck[8];
        #pragma unroll
        for (int k = 0; k < 8; ++k) ck[k] = xs[2*ty + rr][4*tx + 2 + k];
        #pragma unroll
        for (int j = 0; j < 4; ++j) {
            uu[rr][j] = ck[j] - 2.f * ck[j+2] + ck[j+4];
            ww[rr][j] = ck[j] + 4.f * ck[j+1] + 6.f * ck[j+2] + 4.f * ck[j+3] + ck[j+4];
        }
    }

    // ---- own pixel values
    float xv[2][4];
    #pragma unroll
    for (int s = 0; s < 2; ++s)
        #pragma unroll
        for (int j = 0; j < 4; ++j)
            xv[s][j] = xs[2*ty + 2 + s][4*tx + 4 + j];

    // ---- Haar forward+gain+inverse per quad
    float rec[2][4];
    #pragma unroll
    for (int q = 0; q < 2; ++q) {
        const float a = xv[0][2*q], b = xv[0][2*q+1];
        const float c = xv[1][2*q], d = xv[1][2*q+1];
        const float h0 = (a + b + c + d) * 0.5f;
        const float h1 = (a - b + c - d) * 0.5f;
        const float h2 = (a + b - c - d) * 0.5f;
        const float h3 = (a - b - c + d) * 0.5f;
        const float s0 = 0.1f*h0, s1 = 2.5f*h1, s2 = 2.5f*h2, s3 = 3.5f*h3;
        rec[0][2*q]   = (s0 + s1 + s2 + s3) * 0.5f;
        rec[0][2*q+1] = (s0 - s1 + s2 - s3) * 0.5f;
        rec[1][2*q]   = (s0 + s1 - s2 - s3) * 0.5f;
        rec[1][2*q+1] = (s0 - s1 - s2 + s3) * 0.5f;
    }

    // ---- vesselness: vertical combine [1,4,6,4,1]·uu + [1,0,-2,0,1]·ww
    float ves[2][4];
    #pragma unroll
    for (int s = 0; s < 2; ++s) {
        const int gr = r0 + 2*ty + s;
        const bool er = (gr == 0) | (gr == IMG_H - 1);
        #pragma unroll
        for (int j = 0; j < 4; ++j) {
            float t = uu[s][j] + 4.f*uu[s+1][j] + 6.f*uu[s+2][j] + 4.f*uu[s+3][j] + uu[s+4][j]
                    + ww[s][j] - 2.f*ww[s+2][j] + ww[s+4][j];
            float vv = fabsf(t);
            const int gc = c0 + 4*tx + j;
            if (er | (gc == 0) | (gc == IMG_W - 1))
                vv = ves_exact(xs, 2*ty + 2 + s, 4*tx + 4 + j, gr, gc);
            ves[s][j] = vv;
        }
    }

    if constexpr (!WRITE) {
        float rmn = rec[0][0], rmx = rec[0][0];
        float vmn = ves[0][0], vmx = ves[0][0];
        #pragma unroll
        for (int s = 0; s < 2; ++s)
            #pragma unroll
            for (int j = 0; j < 4; ++j) {
                rmn = fminf(rmn, rec[s][j]); rmx = fmaxf(rmx, rec[s][j]);
                vmn = fminf(vmn, ves[s][j]); vmx = fmaxf(vmx, ves[s][j]);
            }
        #pragma unroll
        for (int off = 32; off; off >>= 1) {
            rmn = fminf(rmn, __shfl_down(rmn, off));
            rmx = fmaxf(rmx, __shfl_down(rmx, off));
            vmn = fminf(vmn, __shfl_down(vmn, off));
            vmx = fmaxf(vmx, __shfl_down(vmx, off));
        }
        const int wave = tid >> 6;
        if ((tid & 63) == 0) {
            wred[wave][0] = ford(rmn); wred[wave][1] = ford(rmx);
            wred[wave][2] = ford(vmn); wred[wave][3] = ford(vmx);
        }
        __syncthreads();
        if (tid == 0) {
            uint4 p;
            p.x = min(wred[0][0], wred[1][0]);
            p.y = max(wred[0][1], wred[1][1]);
            p.z = min(wred[0][2], wred[1][2]);
            p.w = max(wred[0][3], wred[1][3]);
            partials[(bimg * 7 + (int)blockIdx.y) * 7 + (int)blockIdx.x] = p;
        }
    } else {
        const float rmin = funord(red[0]), rmax = funord(red[1]);
        const float vmin = funord(red[2]), vmax = funord(red[3]);
        const float rsc = 1.f / (rmax - rmin + 1e-6f);
        const float vsc = 1.f / (vmax - vmin + 1e-6f);
        const float m0 = 0.485f, i0 = 1.f / 0.229f;
        const float m1 = 0.456f, i1 = 1.f / 0.224f;
        const float m2 = 0.406f, i2 = 1.f / 0.225f;

        float* op = out + (size_t)bimg * 3 * PLANE
                        + (size_t)(r0 + 2*ty) * IMG_W + (c0 + 4*tx);
        #pragma unroll
        for (int s = 0; s < 2; ++s) {
            fl4 o0, o1, o2;
            #pragma unroll
            for (int j = 0; j < 4; ++j) {
                o0[j] = (xv[s][j] - m0) * i0;
                o1[j] = ((rec[s][j] - rmin) * rsc - m1) * i1;
                o2[j] = ((ves[s][j] - vmin) * vsc - m2) * i2;
            }
            __builtin_nontemporal_store(o0, (fl4*)(op + s * IMG_W));
            __builtin_nontemporal_store(o1, (fl4*)(op + s * IMG_W + PLANE));
            __builtin_nontemporal_store(o2, (fl4*)(op + s * IMG_W + 2 * PLANE));
        }
    }
}

// 1024-thread single-block reduction of 12544 uint4 partials -> red[0..3]
__global__ __launch_bounds__(1024)
void reduce_partials(const uint4* __restrict__ partials, unsigned int* __restrict__ red)
{
    __shared__ unsigned int wred[16][4];
    const int tid = threadIdx.x;
    unsigned int mn0 = 0xFFFFFFFFu, mx1 = 0u, mn2 = 0xFFFFFFFFu, mx3 = 0u;
    for (int i = tid; i < NTILES; i += 1024) {
        uint4 p = partials[i];
        mn0 = min(mn0, p.x); mx1 = max(mx1, p.y);
        mn2 = min(mn2, p.z); mx3 = max(mx3, p.w);
    }
    #pragma unroll
    for (int off = 32; off; off >>= 1) {
        mn0 = min(mn0, (unsigned)__shfl_down((int)mn0, off));
        mx1 = max(mx1, (unsigned)__shfl_down((int)mx1, off));
        mn2 = min(mn2, (unsigned)__shfl_down((int)mn2, off));
        mx3 = max(mx3, (unsigned)__shfl_down((int)mx3, off));
    }
    const int wave = tid >> 6;
    if ((tid & 63) == 0) {
        wred[wave][0] = mn0; wred[wave][1] = mx1;
        wred[wave][2] = mn2; wred[wave][3] = mx3;
    }
    __syncthreads();
    if (tid == 0) {
        unsigned int a0 = wred[0][0], a1 = wred[0][1], a2 = wred[0][2], a3 = wred[0][3];
        #pragma unroll
        for (int w = 1; w < 16; ++w) {
            a0 = min(a0, wred[w][0]); a1 = max(a1, wred[w][1]);
            a2 = min(a2, wred[w][2]); a3 = max(a3, wred[w][3]);
        }
        red[0] = a0; red[1] = a1; red[2] = a2; red[3] = a3;
    }
}

extern "C" void kernel_launch(void* const* d_in, const int* in_sizes, int n_in,
                              void* d_out, int out_size, void* d_ws, size_t ws_size,
                              hipStream_t stream) {
    const float* x = (const float*)d_in[0];
    float* out = (float*)d_out;
    unsigned int* red = (unsigned int*)d_ws;           // 4 uints
    uint4* partials = (uint4*)((char*)d_ws + 16);      // NTILES uint4

    dim3 grid(7, 7, 256);
    dim3 block(8, 16);
    frac_kernel<false><<<grid, block, 0, stream>>>(x, nullptr, red, partials);
    reduce_partials<<<1, 1024, 0, stream>>>(partials, red);
    frac_kernel<true ><<<grid, block, 0, stream>>>(x, out, red, partials);
}